// Round 5
// baseline (511.123 us; speedup 1.0000x reference)
//
#include <hip/hip_runtime.h>
#include <hip/hip_bf16.h>
#include <math.h>

#define B_ 4
#define T_ 2048
#define C_ 1024
#define H_ 16
#define D_ 64
#define BT (B_*T_)
#define BH (B_*H_)

typedef __bf16 bf16x8 __attribute__((ext_vector_type(8)));
typedef __bf16 bf16x4 __attribute__((ext_vector_type(4)));
typedef float f32x4 __attribute__((ext_vector_type(4)));
typedef unsigned short u16;
typedef u16 u16x8 __attribute__((ext_vector_type(8)));

// async global->LDS, 16B/lane; LDS dest = wave-uniform base + lane*16
#define GLL(g, l) __builtin_amdgcn_global_load_lds( \
    (const __attribute__((address_space(1))) unsigned int*)(g), \
    (__attribute__((address_space(3))) unsigned int*)(l), 16, 0, 0)

__device__ __forceinline__ u16 f2b(float f) {
    union { float f; unsigned u; } v; v.f = f;
    unsigned r = v.u + 0x7fffu + ((v.u >> 16) & 1u);
    return (u16)(r >> 16);
}

// ---------------- cast fp32 -> bf16 (n divisible by 1024) ----------------
__global__ __launch_bounds__(256) void cast_f32_bf16(const float* __restrict__ in,
                                                     u16* __restrict__ out) {
    int g = blockIdx.x * 256 + threadIdx.x;
    float4 x = ((const float4*)in)[g];
    ushort4 o;
    o.x = f2b(x.x); o.y = f2b(x.y); o.z = f2b(x.z); o.w = f2b(x.w);
    ((ushort4*)out)[g] = o;
}

// ------------- Wq/Wk/Wv [H,C,D] fp32 -> [3,H,D,C] bf16 (= [3072,1024]) ----
__global__ __launch_bounds__(256) void transpose_w(const float* __restrict__ Wq,
                                                   const float* __restrict__ Wk,
                                                   const float* __restrict__ Wv,
                                                   u16* __restrict__ out) {
    __shared__ u16 lds[64][72];
    int cb = blockIdx.x, h = blockIdx.y, w = blockIdx.z;
    const float* W = (w == 0) ? Wq : (w == 1) ? Wk : Wv;
    int tid = threadIdx.x;
    int c0 = cb * 64;
    {
        int col = (tid & 15) * 4;
        for (int cc = 0; cc < 4; ++cc) {
            int r = (tid >> 4) + cc * 16;
            float4 x = *(const float4*)&W[(size_t)(h * C_ + c0 + r) * D_ + col];
            lds[r][col + 0] = f2b(x.x); lds[r][col + 1] = f2b(x.y);
            lds[r][col + 2] = f2b(x.z); lds[r][col + 3] = f2b(x.w);
        }
    }
    __syncthreads();
    {
        int tcol = (tid & 7) * 8;
        for (int cc = 0; cc < 2; ++cc) {
            int d = (tid >> 3) + cc * 32;
            u16x8 t;
            for (int j = 0; j < 8; ++j) t[j] = lds[tcol + j][d];
            *(u16x8*)&out[(((size_t)(w * H_ + h) * D_ + d) * C_) + c0 + tcol] = t;
        }
    }
}

// ------- fused QKV GEMM: x[8192,1024] x wt[3072,1024]^T -> q/k/v [BH,T,D] -------
// 128x128 tile; GLL width-16 staging with XOR column swizzle.
__global__ __launch_bounds__(256) void qkv_gemm(const u16* __restrict__ xbf,
                                                const u16* __restrict__ wt,
                                                u16* __restrict__ q, u16* __restrict__ k,
                                                u16* __restrict__ v) {
    __shared__ u16 Al[128][64];
    __shared__ u16 Bl[128][64];
    int mb = blockIdx.x, nb = blockIdx.y;
    int tid = threadIdx.x, wv = tid >> 6, lane = tid & 63, l15 = lane & 15, quad = lane >> 4;
    int rowh = (wv & 1) * 64, colh = (wv >> 1) * 64;
    f32x4 acc[4][4];
    #pragma unroll
    for (int i = 0; i < 4; ++i)
        #pragma unroll
        for (int j = 0; j < 4; ++j) acc[i][j] = (f32x4){0.f, 0.f, 0.f, 0.f};
    int lrow = lane >> 3;                       // 0..7
    int srow = wv * 32 + lrow;
    int scol = (((lane & 7) ^ lrow)) * 8;       // swizzled source column
    const u16* agp = &xbf[(size_t)(mb * 128 + srow) * C_ + scol];
    const u16* bgp = &wt[(size_t)(nb * 128 + srow) * C_ + scol];
    int rsw = l15 & 7;                          // read-side swizzle key
    for (int k0 = 0; k0 < C_; k0 += 64) {
        #pragma unroll
        for (int j = 0; j < 4; ++j) {
            GLL(agp + (size_t)(j * 8) * C_ + k0, &Al[wv * 32 + j * 8][0]);
            GLL(bgp + (size_t)(j * 8) * C_ + k0, &Bl[wv * 32 + j * 8][0]);
        }
        __syncthreads();
        #pragma unroll
        for (int ks = 0; ks < 2; ++ks) {
            int cbl = (((ks << 2) | quad) ^ rsw) * 8;
            bf16x8 af[4], bf[4];
            #pragma unroll
            for (int mt = 0; mt < 4; ++mt)
                af[mt] = *(const bf16x8*)&Al[rowh + mt * 16 + l15][cbl];
            #pragma unroll
            for (int nt = 0; nt < 4; ++nt)
                bf[nt] = *(const bf16x8*)&Bl[colh + nt * 16 + l15][cbl];
            #pragma unroll
            for (int mt = 0; mt < 4; ++mt)
                #pragma unroll
                for (int nt = 0; nt < 4; ++nt)
                    acc[mt][nt] = __builtin_amdgcn_mfma_f32_16x16x32_bf16(af[mt], bf[nt], acc[mt][nt], 0, 0, 0);
        }
        __syncthreads();
    }
    #pragma unroll
    for (int nt = 0; nt < 4; ++nt) {
        int n0 = nb * 128 + colh + nt * 16;
        int wsel = n0 >> 10, hh = (n0 >> 6) & 15, d0 = n0 & 63;
        u16* op = (wsel == 0) ? q : (wsel == 1) ? k : v;
        #pragma unroll
        for (int mt = 0; mt < 4; ++mt)
            #pragma unroll
            for (int r = 0; r < 4; ++r) {
                int m = mb * 128 + rowh + mt * 16 + quad * 4 + r;
                int bb = m >> 11, tt = m & (T_ - 1);
                op[((size_t)(bb * H_ + hh) * T_ + tt) * D_ + d0 + l15] = f2b(acc[mt][nt][r]);
            }
    }
}

// ---------------- V [BH,T,D] -> Vt [BH,D,T] (bf16) ----------------
__global__ __launch_bounds__(256) void vtrans(const u16* __restrict__ v, u16* __restrict__ vt) {
    __shared__ u16 lds[64][72];
    int tb = blockIdx.x, bh = blockIdx.y;
    int t0 = tb * 64, tid = threadIdx.x;
    int col = (tid & 7) * 8;
    for (int cc = 0; cc < 2; ++cc) {
        int r = (tid >> 3) + cc * 32;
        *(u16x8*)&lds[r][col] = *(const u16x8*)&v[((size_t)bh * T_ + t0 + r) * D_ + col];
    }
    __syncthreads();
    for (int cc = 0; cc < 2; ++cc) {
        int d = (tid >> 3) + cc * 32;
        u16x8 t;
        for (int j = 0; j < 8; ++j) t[j] = lds[col + j][d];
        *(u16x8*)&vt[((size_t)bh * D_ + d) * T_ + t0 + col] = t;
    }
}

// -------- flash attention (S^T / O^T form), KV-split x2 -------------------
// Block = 4 waves over one 64-row Q chunk: waves (0,1) rows [0,32),
// waves (2,3) rows [32,64); wave parity takes even/odd KV tiles of [0,c].
// Online-softmax states merged once per chunk via LDS. Grid (16, BH) ->
// 1024 blocks, 4096 waves = 16/CU.
__global__ __launch_bounds__(256, 4) void attn(const u16* __restrict__ q, const u16* __restrict__ kk,
                                               const u16* __restrict__ vt, u16* __restrict__ att) {
    __shared__ u16 Pl[4][32][72];   // per-wave P buffer; reused as merge buffer
    int p = blockIdx.x, bh = blockIdx.y;
    int b = bh >> 4, h = bh & 15;
    int tid = threadIdx.x, wid = tid >> 6, lane = tid & 63, l15 = lane & 15, quad = lane >> 4;
    int half = wid >> 1, s = wid & 1;
    const float scale2 = 0.04508422f;  // C^-0.5 * log2(e)
    const u16* qbase = q + (size_t)bh * T_ * D_;
    const u16* kbase = kk + (size_t)bh * T_ * D_;
    const u16* vbase = vt + (size_t)bh * D_ * T_;
    u16* pw = &Pl[wid][0][0];
    float* xbuf = (float*)&Pl[0][0][0];  // 4608 floats; pair w>>1 gets 2304
    bf16x8 ones;
    #pragma unroll
    for (int j = 0; j < 8; ++j) ones[j] = (__bf16)1.0f;

    for (int ci = 0; ci < 2; ++ci) {
        int c = ci ? (31 - p) : p;
        int R0q = c * 64 + half * 32;
        // Q^T B-frags: B[k=d][n=qrow]
        bf16x8 bq[2][2];
        #pragma unroll
        for (int qt = 0; qt < 2; ++qt)
            #pragma unroll
            for (int kd = 0; kd < 2; ++kd)
                bq[qt][kd] = *(const bf16x8*)&qbase[(size_t)(R0q + qt * 16 + l15) * D_ + kd * 32 + quad * 8];
        f32x4 o[4][2];
        f32x4 lacc[2];
        float m2[2] = {-INFINITY, -INFINITY};
        #pragma unroll
        for (int dt = 0; dt < 4; ++dt)
            #pragma unroll
            for (int qt = 0; qt < 2; ++qt) o[dt][qt] = (f32x4){0.f, 0.f, 0.f, 0.f};
        lacc[0] = (f32x4){0.f, 0.f, 0.f, 0.f};
        lacc[1] = (f32x4){0.f, 0.f, 0.f, 0.f};
        // prefetch K-frags for first tile of this wave's parity
        bf16x8 akn[4][2];
        #pragma unroll
        for (int kvt = 0; kvt < 4; ++kvt)
            #pragma unroll
            for (int kd = 0; kd < 2; ++kd)
                akn[kvt][kd] = *(const bf16x8*)&kbase[(size_t)(s * 64 + kvt * 16 + l15) * D_ + kd * 32 + quad * 8];
        for (int kt = s; kt <= c; kt += 2) {
            int k0 = kt * 64;
            bf16x8 ak[4][2];
            #pragma unroll
            for (int kvt = 0; kvt < 4; ++kvt)
                #pragma unroll
                for (int kd = 0; kd < 2; ++kd) ak[kvt][kd] = akn[kvt][kd];
            if (kt + 2 <= c) {  // issue next (same-parity) tile's K now
                int kn = k0 + 128;
                #pragma unroll
                for (int kvt = 0; kvt < 4; ++kvt)
                    #pragma unroll
                    for (int kd = 0; kd < 2; ++kd)
                        akn[kvt][kd] = *(const bf16x8*)&kbase[(size_t)(kn + kvt * 16 + l15) * D_ + kd * 32 + quad * 8];
            }
            // S^T = K . Q^T : C col = qrow(l15), row = kv(quad*4+r)
            f32x4 sS[4][2];
            #pragma unroll
            for (int kvt = 0; kvt < 4; ++kvt)
                #pragma unroll
                for (int qt = 0; qt < 2; ++qt) sS[kvt][qt] = (f32x4){0.f, 0.f, 0.f, 0.f};
            #pragma unroll
            for (int kd = 0; kd < 2; ++kd)
                #pragma unroll
                for (int kvt = 0; kvt < 4; ++kvt)
                    #pragma unroll
                    for (int qt = 0; qt < 2; ++qt)
                        sS[kvt][qt] = __builtin_amdgcn_mfma_f32_16x16x32_bf16(ak[kvt][kd], bq[qt][kd], sS[kvt][qt], 0, 0, 0);
            // V^T A-frags: issued here, consumed after softmax (latency hidden)
            bf16x8 av[4][2];
            #pragma unroll
            for (int dt = 0; dt < 4; ++dt)
                #pragma unroll
                for (int ks = 0; ks < 2; ++ks)
                    av[dt][ks] = *(const bf16x8*)&vbase[(size_t)(dt * 16 + l15) * T_ + k0 + ks * 32 + quad * 8];
            if (kt == c) {  // causal mask, diagonal tile only
                #pragma unroll
                for (int qt = 0; qt < 2; ++qt) {
                    int qabs = R0q + qt * 16 + l15;
                    #pragma unroll
                    for (int kvt = 0; kvt < 4; ++kvt) {
                        int kvb = k0 + kvt * 16 + quad * 4;
                        #pragma unroll
                        for (int r = 0; r < 4; ++r)
                            if (kvb + r > qabs) sS[kvt][qt][r] = -INFINITY;
                    }
                }
            }
            // online softmax (exp2 domain): 16 in-lane fmax + 2 shfl per qt
            float alpha[2];
            #pragma unroll
            for (int qt = 0; qt < 2; ++qt) {
                float vm = sS[0][qt][0];
                #pragma unroll
                for (int kvt = 0; kvt < 4; ++kvt)
                    #pragma unroll
                    for (int r = 0; r < 4; ++r) vm = fmaxf(vm, sS[kvt][qt][r]);
                vm = fmaxf(vm, __shfl_xor(vm, 16));
                vm = fmaxf(vm, __shfl_xor(vm, 32));
                float mn = fmaxf(m2[qt], vm * scale2);
                alpha[qt] = __builtin_amdgcn_exp2f(m2[qt] - mn);
                m2[qt] = mn;
            }
            #pragma unroll
            for (int kvt = 0; kvt < 4; ++kvt)
                #pragma unroll
                for (int qt = 0; qt < 2; ++qt)
                    #pragma unroll
                    for (int r = 0; r < 4; ++r)
                        sS[kvt][qt][r] = __builtin_amdgcn_exp2f(fmaf(sS[kvt][qt][r], scale2, -m2[qt]));
            #pragma unroll
            for (int dt = 0; dt < 4; ++dt)
                #pragma unroll
                for (int qt = 0; qt < 2; ++qt)
                    #pragma unroll
                    for (int r = 0; r < 4; ++r) o[dt][qt][r] *= alpha[qt];
            #pragma unroll
            for (int qt = 0; qt < 2; ++qt)
                #pragma unroll
                for (int r = 0; r < 4; ++r) lacc[qt][r] *= alpha[qt];
            // P -> wave-private LDS: P[qrow][kv] (bf16)
            #pragma unroll
            for (int qt = 0; qt < 2; ++qt)
                #pragma unroll
                for (int kvt = 0; kvt < 4; ++kvt) {
                    bf16x4 w;
                    #pragma unroll
                    for (int r = 0; r < 4; ++r) w[r] = (__bf16)sS[kvt][qt][r];
                    *(bf16x4*)&pw[(qt * 16 + l15) * 72 + kvt * 16 + quad * 4] = w;
                }
            // O^T += V^T . P^T ; l += ones . P^T
            #pragma unroll
            for (int qt = 0; qt < 2; ++qt)
                #pragma unroll
                for (int ks = 0; ks < 2; ++ks) {
                    bf16x8 bp = *(const bf16x8*)&pw[(qt * 16 + l15) * 72 + ks * 32 + quad * 8];
                    #pragma unroll
                    for (int dt = 0; dt < 4; ++dt)
                        o[dt][qt] = __builtin_amdgcn_mfma_f32_16x16x32_bf16(av[dt][ks], bp, o[dt][qt], 0, 0, 0);
                    lacc[qt] = __builtin_amdgcn_mfma_f32_16x16x32_bf16(ones, bp, lacc[qt], 0, 0, 0);
                }
        }
        // ---- merge wave pair (s=1 partial -> s=0), then s=0 stores ----
        __syncthreads();   // all waves done reading their own Pl region
        if (s == 1) {
            float* dst = xbuf + half * 2304 + lane;
            #pragma unroll
            for (int dt = 0; dt < 4; ++dt)
                #pragma unroll
                for (int qt = 0; qt < 2; ++qt)
                    #pragma unroll
                    for (int r = 0; r < 4; ++r)
                        dst[((dt * 2 + qt) * 4 + r) * 64] = o[dt][qt][r];
            dst[32 * 64] = m2[0];
            dst[33 * 64] = m2[1];
            dst[34 * 64] = lacc[0][0];
            dst[35 * 64] = lacc[1][0];
        }
        __syncthreads();
        if (s == 0) {
            const float* src = xbuf + half * 2304 + lane;
            float mbs[2] = {src[32 * 64], src[33 * 64]};
            float lbs[2] = {src[34 * 64], src[35 * 64]};
            #pragma unroll
            for (int qt = 0; qt < 2; ++qt) {
                float mm = fmaxf(m2[qt], mbs[qt]);
                float fa = __builtin_amdgcn_exp2f(m2[qt] - mm);
                float fb = __builtin_amdgcn_exp2f(mbs[qt] - mm);
                float ll = lacc[qt][0] * fa + lbs[qt] * fb;
                float rl = __builtin_amdgcn_rcpf(ll);
                int qabs = R0q + qt * 16 + l15;
                #pragma unroll
                for (int dt = 0; dt < 4; ++dt) {
                    bf16x4 w;
                    #pragma unroll
                    for (int r = 0; r < 4; ++r) {
                        float ov = o[dt][qt][r] * fa + src[((dt * 2 + qt) * 4 + r) * 64] * fb;
                        w[r] = (__bf16)(ov * rl);
                    }
                    *(bf16x4*)&att[(size_t)(b * T_ + qabs) * C_ + h * 64 + dt * 16 + quad * 4] = w;
                }
            }
        }
        __syncthreads();   // protect merge buffer before next ci reuses Pl
    }
}

// ------ out proj: att[8192,1024] x wo[1024,1024]^T + bo -> fp32 out -------
__global__ __launch_bounds__(256) void out_gemm(const u16* __restrict__ att,
                                                const u16* __restrict__ wo,
                                                const float* __restrict__ bo,
                                                float* __restrict__ out) {
    __shared__ u16 Al[128][64];
    __shared__ u16 Bl[128][64];
    int mb = blockIdx.x, nb = blockIdx.y;
    int tid = threadIdx.x, wv = tid >> 6, lane = tid & 63, l15 = lane & 15, quad = lane >> 4;
    int rowh = (wv & 1) * 64, colh = (wv >> 1) * 64;
    f32x4 acc[4][4];
    #pragma unroll
    for (int i = 0; i < 4; ++i)
        #pragma unroll
        for (int j = 0; j < 4; ++j) acc[i][j] = (f32x4){0.f, 0.f, 0.f, 0.f};
    int lrow = lane >> 3;
    int srow = wv * 32 + lrow;
    int scol = (((lane & 7) ^ lrow)) * 8;
    const u16* agp = &att[(size_t)(mb * 128 + srow) * C_ + scol];
    const u16* bgp = &wo[(size_t)(nb * 128 + srow) * C_ + scol];
    int rsw = l15 & 7;
    for (int k0 = 0; k0 < C_; k0 += 64) {
        #pragma unroll
        for (int j = 0; j < 4; ++j) {
            GLL(agp + (size_t)(j * 8) * C_ + k0, &Al[wv * 32 + j * 8][0]);
            GLL(bgp + (size_t)(j * 8) * C_ + k0, &Bl[wv * 32 + j * 8][0]);
        }
        __syncthreads();
        #pragma unroll
        for (int ks = 0; ks < 2; ++ks) {
            int cbl = (((ks << 2) | quad) ^ rsw) * 8;
            bf16x8 af[4], bf[4];
            #pragma unroll
            for (int mt = 0; mt < 4; ++mt)
                af[mt] = *(const bf16x8*)&Al[rowh + mt * 16 + l15][cbl];
            #pragma unroll
            for (int nt = 0; nt < 4; ++nt)
                bf[nt] = *(const bf16x8*)&Bl[colh + nt * 16 + l15][cbl];
            #pragma unroll
            for (int mt = 0; mt < 4; ++mt)
                #pragma unroll
                for (int nt = 0; nt < 4; ++nt)
                    acc[mt][nt] = __builtin_amdgcn_mfma_f32_16x16x32_bf16(af[mt], bf[nt], acc[mt][nt], 0, 0, 0);
        }
        __syncthreads();
    }
    #pragma unroll
    for (int nt = 0; nt < 4; ++nt) {
        int n = nb * 128 + colh + nt * 16 + l15;
        float bias = bo[n];
        #pragma unroll
        for (int mt = 0; mt < 4; ++mt)
            #pragma unroll
            for (int r = 0; r < 4; ++r) {
                int m = mb * 128 + rowh + mt * 16 + quad * 4 + r;
                out[(size_t)m * C_ + n] = acc[mt][nt][r] + bias;
            }
    }
}

extern "C" void kernel_launch(void* const* d_in, const int* in_sizes, int n_in,
                              void* d_out, int out_size, void* d_ws, size_t ws_size,
                              hipStream_t stream) {
    const float* x  = (const float*)d_in[0];
    const float* Wq = (const float*)d_in[1];
    const float* Wk = (const float*)d_in[2];
    const float* Wv = (const float*)d_in[3];
    const float* Wo = (const float*)d_in[4];
    const float* bo = (const float*)d_in[5];
    float* out = (float*)d_out;
    char* ws = (char*)d_ws;
    u16* xbf  = (u16*)(ws + (size_t)0);           // 16 MB  x bf16 [8192,1024]
    u16* wt   = (u16*)(ws + ((size_t)16 << 20));  //  6 MB  W qkv [3072,1024] bf16
    u16* wobf = (u16*)(ws + ((size_t)22 << 20));  //  2 MB  Wo bf16 [1024,1024]
    u16* qb   = (u16*)(ws + ((size_t)24 << 20));  // 16 MB  q [BH,T,D]
    u16* kb   = (u16*)(ws + ((size_t)40 << 20));  // 16 MB  k [BH,T,D]
    u16* vb   = (u16*)(ws + ((size_t)56 << 20));  // 16 MB  v [BH,T,D]
    u16* vtb  = (u16*)(ws + ((size_t)72 << 20));  // 16 MB  v^T [BH,D,T]
    u16* attb = (u16*)(ws + ((size_t)88 << 20));  // 16 MB  att out [B*T,C]

    hipLaunchKernelGGL(cast_f32_bf16, dim3(BT * C_ / 1024), dim3(256), 0, stream, x, xbf);
    hipLaunchKernelGGL(cast_f32_bf16, dim3(C_ * C_ / 1024), dim3(256), 0, stream, Wo, wobf);
    hipLaunchKernelGGL(transpose_w, dim3(C_ / 64, H_, 3), dim3(256), 0, stream, Wq, Wk, Wv, wt);
    hipLaunchKernelGGL(qkv_gemm, dim3(BT / 128, 3 * C_ / 128), dim3(256), 0, stream, xbf, wt, qb, kb, vb);
    hipLaunchKernelGGL(vtrans, dim3(T_ / 64, BH), dim3(256), 0, stream, vb, vtb);
    hipLaunchKernelGGL(attn, dim3(16, BH), dim3(256), 0, stream, qb, kb, vtb, attb);
    hipLaunchKernelGGL(out_gemm, dim3(BT / 128, C_ / 128), dim3(256), 0, stream, attb, wobf, bo, out);
}

// Round 6
// 304.197 us; speedup vs baseline: 1.6802x; 1.6802x over previous
//
#include <hip/hip_runtime.h>
#include <hip/hip_bf16.h>
#include <math.h>

#define B_ 4
#define T_ 2048
#define C_ 1024
#define H_ 16
#define D_ 64
#define BT (B_*T_)
#define BH (B_*H_)

typedef __bf16 bf16x8 __attribute__((ext_vector_type(8)));
typedef __bf16 bf16x4 __attribute__((ext_vector_type(4)));
typedef float f32x4 __attribute__((ext_vector_type(4)));
typedef unsigned short u16;
typedef u16 u16x8 __attribute__((ext_vector_type(8)));

// async global->LDS, 16B/lane; LDS dest = wave-uniform base + lane*16
#define GLL(g, l) __builtin_amdgcn_global_load_lds( \
    (const __attribute__((address_space(1))) unsigned int*)(g), \
    (__attribute__((address_space(3))) unsigned int*)(l), 16, 0, 0)

__device__ __forceinline__ u16 f2b(float f) {
    union { float f; unsigned u; } v; v.f = f;
    unsigned r = v.u + 0x7fffu + ((v.u >> 16) & 1u);
    return (u16)(r >> 16);
}

// ---------------- cast fp32 -> bf16 (n divisible by 1024) ----------------
__global__ __launch_bounds__(256) void cast_f32_bf16(const float* __restrict__ in,
                                                     u16* __restrict__ out) {
    int g = blockIdx.x * 256 + threadIdx.x;
    float4 x = ((const float4*)in)[g];
    ushort4 o;
    o.x = f2b(x.x); o.y = f2b(x.y); o.z = f2b(x.z); o.w = f2b(x.w);
    ((ushort4*)out)[g] = o;
}

// ------------- Wq/Wk/Wv [H,C,D] fp32 -> [3,H,D,C] bf16 (= [3072,1024]) ----
__global__ __launch_bounds__(256) void transpose_w(const float* __restrict__ Wq,
                                                   const float* __restrict__ Wk,
                                                   const float* __restrict__ Wv,
                                                   u16* __restrict__ out) {
    __shared__ u16 lds[64][72];
    int cb = blockIdx.x, h = blockIdx.y, w = blockIdx.z;
    const float* W = (w == 0) ? Wq : (w == 1) ? Wk : Wv;
    int tid = threadIdx.x;
    int c0 = cb * 64;
    {
        int col = (tid & 15) * 4;
        for (int cc = 0; cc < 4; ++cc) {
            int r = (tid >> 4) + cc * 16;
            float4 x = *(const float4*)&W[(size_t)(h * C_ + c0 + r) * D_ + col];
            lds[r][col + 0] = f2b(x.x); lds[r][col + 1] = f2b(x.y);
            lds[r][col + 2] = f2b(x.z); lds[r][col + 3] = f2b(x.w);
        }
    }
    __syncthreads();
    {
        int tcol = (tid & 7) * 8;
        for (int cc = 0; cc < 2; ++cc) {
            int d = (tid >> 3) + cc * 32;
            u16x8 t;
            for (int j = 0; j < 8; ++j) t[j] = lds[tcol + j][d];
            *(u16x8*)&out[(((size_t)(w * H_ + h) * D_ + d) * C_) + c0 + tcol] = t;
        }
    }
}

// ------- fused QKV GEMM: x[8192,1024] x wt[3072,1024]^T -> q/k/v [BH,T,D] -------
// 128x128 tile; GLL width-16 staging with XOR column swizzle.
__global__ __launch_bounds__(256) void qkv_gemm(const u16* __restrict__ xbf,
                                                const u16* __restrict__ wt,
                                                u16* __restrict__ q, u16* __restrict__ k,
                                                u16* __restrict__ v) {
    __shared__ u16 Al[128][64];
    __shared__ u16 Bl[128][64];
    int mb = blockIdx.x, nb = blockIdx.y;
    int tid = threadIdx.x, wv = tid >> 6, lane = tid & 63, l15 = lane & 15, quad = lane >> 4;
    int rowh = (wv & 1) * 64, colh = (wv >> 1) * 64;
    f32x4 acc[4][4];
    #pragma unroll
    for (int i = 0; i < 4; ++i)
        #pragma unroll
        for (int j = 0; j < 4; ++j) acc[i][j] = (f32x4){0.f, 0.f, 0.f, 0.f};
    int lrow = lane >> 3;                       // 0..7
    int srow = wv * 32 + lrow;
    int scol = (((lane & 7) ^ lrow)) * 8;       // swizzled source column
    const u16* agp = &xbf[(size_t)(mb * 128 + srow) * C_ + scol];
    const u16* bgp = &wt[(size_t)(nb * 128 + srow) * C_ + scol];
    int rsw = l15 & 7;                          // read-side swizzle key
    for (int k0 = 0; k0 < C_; k0 += 64) {
        #pragma unroll
        for (int j = 0; j < 4; ++j) {
            GLL(agp + (size_t)(j * 8) * C_ + k0, &Al[wv * 32 + j * 8][0]);
            GLL(bgp + (size_t)(j * 8) * C_ + k0, &Bl[wv * 32 + j * 8][0]);
        }
        __syncthreads();
        #pragma unroll
        for (int ks = 0; ks < 2; ++ks) {
            int cbl = (((ks << 2) | quad) ^ rsw) * 8;
            bf16x8 af[4], bf[4];
            #pragma unroll
            for (int mt = 0; mt < 4; ++mt)
                af[mt] = *(const bf16x8*)&Al[rowh + mt * 16 + l15][cbl];
            #pragma unroll
            for (int nt = 0; nt < 4; ++nt)
                bf[nt] = *(const bf16x8*)&Bl[colh + nt * 16 + l15][cbl];
            #pragma unroll
            for (int mt = 0; mt < 4; ++mt)
                #pragma unroll
                for (int nt = 0; nt < 4; ++nt)
                    acc[mt][nt] = __builtin_amdgcn_mfma_f32_16x16x32_bf16(af[mt], bf[nt], acc[mt][nt], 0, 0, 0);
        }
        __syncthreads();
    }
    #pragma unroll
    for (int nt = 0; nt < 4; ++nt) {
        int n0 = nb * 128 + colh + nt * 16;
        int wsel = n0 >> 10, hh = (n0 >> 6) & 15, d0 = n0 & 63;
        u16* op = (wsel == 0) ? q : (wsel == 1) ? k : v;
        #pragma unroll
        for (int mt = 0; mt < 4; ++mt)
            #pragma unroll
            for (int r = 0; r < 4; ++r) {
                int m = mb * 128 + rowh + mt * 16 + quad * 4 + r;
                int bb = m >> 11, tt = m & (T_ - 1);
                op[((size_t)(bb * H_ + hh) * T_ + tt) * D_ + d0 + l15] = f2b(acc[mt][nt][r]);
            }
    }
}

// ---------------- V [BH,T,D] -> Vt [BH,D,T] (bf16) ----------------
__global__ __launch_bounds__(256) void vtrans(const u16* __restrict__ v, u16* __restrict__ vt) {
    __shared__ u16 lds[64][72];
    int tb = blockIdx.x, bh = blockIdx.y;
    int t0 = tb * 64, tid = threadIdx.x;
    int col = (tid & 7) * 8;
    for (int cc = 0; cc < 2; ++cc) {
        int r = (tid >> 3) + cc * 32;
        *(u16x8*)&lds[r][col] = *(const u16x8*)&v[((size_t)bh * T_ + t0 + r) * D_ + col];
    }
    __syncthreads();
    for (int cc = 0; cc < 2; ++cc) {
        int d = (tid >> 3) + cc * 32;
        u16x8 t;
        for (int j = 0; j < 8; ++j) t[j] = lds[col + j][d];
        *(u16x8*)&vt[((size_t)bh * D_ + d) * T_ + t0 + col] = t;
    }
}

// -------- flash attention (S^T / O^T form), KV-split x2 -------------------
// Block = 4 waves over one 64-row Q chunk: waves (0,1) rows [0,32),
// waves (2,3) rows [32,64); wave parity takes even/odd KV tiles of [0,c].
// Online-softmax states merged once per chunk via LDS. Grid (16, BH) ->
// 1024 blocks, 4096 waves = 16/CU.
// NOTE: (256,2) not (256,4): the 4-wave cap forced VGPR 64 + scratch spill
// (R5: WRITE_SIZE 16->622 MB). Natural allocation is ~116 VGPR -> 4 waves/EU.
__global__ __launch_bounds__(256, 2) void attn(const u16* __restrict__ q, const u16* __restrict__ kk,
                                               const u16* __restrict__ vt, u16* __restrict__ att) {
    __shared__ u16 Pl[4][32][72];   // per-wave P buffer; reused as merge buffer
    int p = blockIdx.x, bh = blockIdx.y;
    int b = bh >> 4, h = bh & 15;
    int tid = threadIdx.x, wid = tid >> 6, lane = tid & 63, l15 = lane & 15, quad = lane >> 4;
    int half = wid >> 1, s = wid & 1;
    const float scale2 = 0.04508422f;  // C^-0.5 * log2(e)
    const u16* qbase = q + (size_t)bh * T_ * D_;
    const u16* kbase = kk + (size_t)bh * T_ * D_;
    const u16* vbase = vt + (size_t)bh * D_ * T_;
    u16* pw = &Pl[wid][0][0];
    float* xbuf = (float*)&Pl[0][0][0];  // merge buffer; pair (wid>>1) gets 2304 floats
    bf16x8 ones;
    #pragma unroll
    for (int j = 0; j < 8; ++j) ones[j] = (__bf16)1.0f;

    for (int ci = 0; ci < 2; ++ci) {
        int c = ci ? (31 - p) : p;
        int R0q = c * 64 + half * 32;
        // Q^T B-frags: B[k=d][n=qrow]
        bf16x8 bq[2][2];
        #pragma unroll
        for (int qt = 0; qt < 2; ++qt)
            #pragma unroll
            for (int kd = 0; kd < 2; ++kd)
                bq[qt][kd] = *(const bf16x8*)&qbase[(size_t)(R0q + qt * 16 + l15) * D_ + kd * 32 + quad * 8];
        f32x4 o[4][2];
        f32x4 lacc[2];
        float m2[2] = {-INFINITY, -INFINITY};
        #pragma unroll
        for (int dt = 0; dt < 4; ++dt)
            #pragma unroll
            for (int qt = 0; qt < 2; ++qt) o[dt][qt] = (f32x4){0.f, 0.f, 0.f, 0.f};
        lacc[0] = (f32x4){0.f, 0.f, 0.f, 0.f};
        lacc[1] = (f32x4){0.f, 0.f, 0.f, 0.f};
        // prefetch K-frags for first tile of this wave's parity
        bf16x8 akn[4][2];
        #pragma unroll
        for (int kvt = 0; kvt < 4; ++kvt)
            #pragma unroll
            for (int kd = 0; kd < 2; ++kd)
                akn[kvt][kd] = *(const bf16x8*)&kbase[(size_t)(s * 64 + kvt * 16 + l15) * D_ + kd * 32 + quad * 8];
        for (int kt = s; kt <= c; kt += 2) {
            int k0 = kt * 64;
            bf16x8 ak[4][2];
            #pragma unroll
            for (int kvt = 0; kvt < 4; ++kvt)
                #pragma unroll
                for (int kd = 0; kd < 2; ++kd) ak[kvt][kd] = akn[kvt][kd];
            if (kt + 2 <= c) {  // issue next (same-parity) tile's K now
                int kn = k0 + 128;
                #pragma unroll
                for (int kvt = 0; kvt < 4; ++kvt)
                    #pragma unroll
                    for (int kd = 0; kd < 2; ++kd)
                        akn[kvt][kd] = *(const bf16x8*)&kbase[(size_t)(kn + kvt * 16 + l15) * D_ + kd * 32 + quad * 8];
            }
            // S^T = K . Q^T : C col = qrow(l15), row = kv(quad*4+r)
            f32x4 sS[4][2];
            #pragma unroll
            for (int kvt = 0; kvt < 4; ++kvt)
                #pragma unroll
                for (int qt = 0; qt < 2; ++qt) sS[kvt][qt] = (f32x4){0.f, 0.f, 0.f, 0.f};
            #pragma unroll
            for (int kd = 0; kd < 2; ++kd)
                #pragma unroll
                for (int kvt = 0; kvt < 4; ++kvt)
                    #pragma unroll
                    for (int qt = 0; qt < 2; ++qt)
                        sS[kvt][qt] = __builtin_amdgcn_mfma_f32_16x16x32_bf16(ak[kvt][kd], bq[qt][kd], sS[kvt][qt], 0, 0, 0);
            // V^T A-frags: issued here, consumed after softmax (latency hidden)
            bf16x8 av[4][2];
            #pragma unroll
            for (int dt = 0; dt < 4; ++dt)
                #pragma unroll
                for (int ks = 0; ks < 2; ++ks)
                    av[dt][ks] = *(const bf16x8*)&vbase[(size_t)(dt * 16 + l15) * T_ + k0 + ks * 32 + quad * 8];
            if (kt == c) {  // causal mask, diagonal tile only
                #pragma unroll
                for (int qt = 0; qt < 2; ++qt) {
                    int qabs = R0q + qt * 16 + l15;
                    #pragma unroll
                    for (int kvt = 0; kvt < 4; ++kvt) {
                        int kvb = k0 + kvt * 16 + quad * 4;
                        #pragma unroll
                        for (int r = 0; r < 4; ++r)
                            if (kvb + r > qabs) sS[kvt][qt][r] = -INFINITY;
                    }
                }
            }
            // online softmax (exp2 domain): 16 in-lane fmax + 2 shfl per qt
            float alpha[2];
            #pragma unroll
            for (int qt = 0; qt < 2; ++qt) {
                float vm = sS[0][qt][0];
                #pragma unroll
                for (int kvt = 0; kvt < 4; ++kvt)
                    #pragma unroll
                    for (int r = 0; r < 4; ++r) vm = fmaxf(vm, sS[kvt][qt][r]);
                vm = fmaxf(vm, __shfl_xor(vm, 16));
                vm = fmaxf(vm, __shfl_xor(vm, 32));
                float mn = fmaxf(m2[qt], vm * scale2);
                alpha[qt] = __builtin_amdgcn_exp2f(m2[qt] - mn);
                m2[qt] = mn;
            }
            #pragma unroll
            for (int kvt = 0; kvt < 4; ++kvt)
                #pragma unroll
                for (int qt = 0; qt < 2; ++qt)
                    #pragma unroll
                    for (int r = 0; r < 4; ++r)
                        sS[kvt][qt][r] = __builtin_amdgcn_exp2f(fmaf(sS[kvt][qt][r], scale2, -m2[qt]));
            #pragma unroll
            for (int dt = 0; dt < 4; ++dt)
                #pragma unroll
                for (int qt = 0; qt < 2; ++qt)
                    #pragma unroll
                    for (int r = 0; r < 4; ++r) o[dt][qt][r] *= alpha[qt];
            #pragma unroll
            for (int qt = 0; qt < 2; ++qt)
                #pragma unroll
                for (int r = 0; r < 4; ++r) lacc[qt][r] *= alpha[qt];
            // P -> wave-private LDS: P[qrow][kv] (bf16)
            #pragma unroll
            for (int qt = 0; qt < 2; ++qt)
                #pragma unroll
                for (int kvt = 0; kvt < 4; ++kvt) {
                    bf16x4 w;
                    #pragma unroll
                    for (int r = 0; r < 4; ++r) w[r] = (__bf16)sS[kvt][qt][r];
                    *(bf16x4*)&pw[(qt * 16 + l15) * 72 + kvt * 16 + quad * 4] = w;
                }
            // O^T += V^T . P^T ; l += ones . P^T
            #pragma unroll
            for (int qt = 0; qt < 2; ++qt)
                #pragma unroll
                for (int ks = 0; ks < 2; ++ks) {
                    bf16x8 bp = *(const bf16x8*)&pw[(qt * 16 + l15) * 72 + ks * 32 + quad * 8];
                    #pragma unroll
                    for (int dt = 0; dt < 4; ++dt)
                        o[dt][qt] = __builtin_amdgcn_mfma_f32_16x16x32_bf16(av[dt][ks], bp, o[dt][qt], 0, 0, 0);
                    lacc[qt] = __builtin_amdgcn_mfma_f32_16x16x32_bf16(ones, bp, lacc[qt], 0, 0, 0);
                }
        }
        // ---- merge wave pair (s=1 partial -> s=0), then s=0 stores ----
        __syncthreads();   // all waves done reading their own Pl region
        if (s == 1) {
            float* dst = xbuf + half * 2304 + lane;
            #pragma unroll
            for (int dt = 0; dt < 4; ++dt)
                #pragma unroll
                for (int qt = 0; qt < 2; ++qt)
                    #pragma unroll
                    for (int r = 0; r < 4; ++r)
                        dst[((dt * 2 + qt) * 4 + r) * 64] = o[dt][qt][r];
            dst[32 * 64] = m2[0];
            dst[33 * 64] = m2[1];
            dst[34 * 64] = lacc[0][0];
            dst[35 * 64] = lacc[1][0];
        }
        __syncthreads();
        if (s == 0) {
            const float* src = xbuf + half * 2304 + lane;
            float mbs[2] = {src[32 * 64], src[33 * 64]};
            float lbs[2] = {src[34 * 64], src[35 * 64]};
            #pragma unroll
            for (int qt = 0; qt < 2; ++qt) {
                float mm = fmaxf(m2[qt], mbs[qt]);
                float fa = __builtin_amdgcn_exp2f(m2[qt] - mm);
                float fb = __builtin_amdgcn_exp2f(mbs[qt] - mm);
                float ll = lacc[qt][0] * fa + lbs[qt] * fb;
                float rl = __builtin_amdgcn_rcpf(ll);
                int qabs = R0q + qt * 16 + l15;
                #pragma unroll
                for (int dt = 0; dt < 4; ++dt) {
                    bf16x4 w;
                    #pragma unroll
                    for (int r = 0; r < 4; ++r) {
                        float ov = o[dt][qt][r] * fa + src[((dt * 2 + qt) * 4 + r) * 64] * fb;
                        w[r] = (__bf16)(ov * rl);
                    }
                    *(bf16x4*)&att[(size_t)(b * T_ + qabs) * C_ + h * 64 + dt * 16 + quad * 4] = w;
                }
            }
        }
        __syncthreads();   // protect merge buffer before next ci reuses Pl
    }
}

// ------ out proj: att[8192,1024] x wo[1024,1024]^T + bo -> fp32 out -------
__global__ __launch_bounds__(256) void out_gemm(const u16* __restrict__ att,
                                                const u16* __restrict__ wo,
                                                const float* __restrict__ bo,
                                                float* __restrict__ out) {
    __shared__ u16 Al[128][64];
    __shared__ u16 Bl[128][64];
    int mb = blockIdx.x, nb = blockIdx.y;
    int tid = threadIdx.x, wv = tid >> 6, lane = tid & 63, l15 = lane & 15, quad = lane >> 4;
    int rowh = (wv & 1) * 64, colh = (wv >> 1) * 64;
    f32x4 acc[4][4];
    #pragma unroll
    for (int i = 0; i < 4; ++i)
        #pragma unroll
        for (int j = 0; j < 4; ++j) acc[i][j] = (f32x4){0.f, 0.f, 0.f, 0.f};
    int lrow = lane >> 3;
    int srow = wv * 32 + lrow;
    int scol = (((lane & 7) ^ lrow)) * 8;
    const u16* agp = &att[(size_t)(mb * 128 + srow) * C_ + scol];
    const u16* bgp = &wo[(size_t)(nb * 128 + srow) * C_ + scol];
    int rsw = l15 & 7;
    for (int k0 = 0; k0 < C_; k0 += 64) {
        #pragma unroll
        for (int j = 0; j < 4; ++j) {
            GLL(agp + (size_t)(j * 8) * C_ + k0, &Al[wv * 32 + j * 8][0]);
            GLL(bgp + (size_t)(j * 8) * C_ + k0, &Bl[wv * 32 + j * 8][0]);
        }
        __syncthreads();
        #pragma unroll
        for (int ks = 0; ks < 2; ++ks) {
            int cbl = (((ks << 2) | quad) ^ rsw) * 8;
            bf16x8 af[4], bf[4];
            #pragma unroll
            for (int mt = 0; mt < 4; ++mt)
                af[mt] = *(const bf16x8*)&Al[rowh + mt * 16 + l15][cbl];
            #pragma unroll
            for (int nt = 0; nt < 4; ++nt)
                bf[nt] = *(const bf16x8*)&Bl[colh + nt * 16 + l15][cbl];
            #pragma unroll
            for (int mt = 0; mt < 4; ++mt)
                #pragma unroll
                for (int nt = 0; nt < 4; ++nt)
                    acc[mt][nt] = __builtin_amdgcn_mfma_f32_16x16x32_bf16(af[mt], bf[nt], acc[mt][nt], 0, 0, 0);
        }
        __syncthreads();
    }
    #pragma unroll
    for (int nt = 0; nt < 4; ++nt) {
        int n = nb * 128 + colh + nt * 16 + l15;
        float bias = bo[n];
        #pragma unroll
        for (int mt = 0; mt < 4; ++mt)
            #pragma unroll
            for (int r = 0; r < 4; ++r) {
                int m = mb * 128 + rowh + mt * 16 + quad * 4 + r;
                out[(size_t)m * C_ + n] = acc[mt][nt][r] + bias;
            }
    }
}

extern "C" void kernel_launch(void* const* d_in, const int* in_sizes, int n_in,
                              void* d_out, int out_size, void* d_ws, size_t ws_size,
                              hipStream_t stream) {
    const float* x  = (const float*)d_in[0];
    const float* Wq = (const float*)d_in[1];
    const float* Wk = (const float*)d_in[2];
    const float* Wv = (const float*)d_in[3];
    const float* Wo = (const float*)d_in[4];
    const float* bo = (const float*)d_in[5];
    float* out = (float*)d_out;
    char* ws = (char*)d_ws;
    u16* xbf  = (u16*)(ws + (size_t)0);           // 16 MB  x bf16 [8192,1024]
    u16* wt   = (u16*)(ws + ((size_t)16 << 20));  //  6 MB  W qkv [3072,1024] bf16
    u16* wobf = (u16*)(ws + ((size_t)22 << 20));  //  2 MB  Wo bf16 [1024,1024]
    u16* qb   = (u16*)(ws + ((size_t)24 << 20));  // 16 MB  q [BH,T,D]
    u16* kb   = (u16*)(ws + ((size_t)40 << 20));  // 16 MB  k [BH,T,D]
    u16* vb   = (u16*)(ws + ((size_t)56 << 20));  // 16 MB  v [BH,T,D]
    u16* vtb  = (u16*)(ws + ((size_t)72 << 20));  // 16 MB  v^T [BH,D,T]
    u16* attb = (u16*)(ws + ((size_t)88 << 20));  // 16 MB  att out [B*T,C]

    hipLaunchKernelGGL(cast_f32_bf16, dim3(BT * C_ / 1024), dim3(256), 0, stream, x, xbf);
    hipLaunchKernelGGL(cast_f32_bf16, dim3(C_ * C_ / 1024), dim3(256), 0, stream, Wo, wobf);
    hipLaunchKernelGGL(transpose_w, dim3(C_ / 64, H_, 3), dim3(256), 0, stream, Wq, Wk, Wv, wt);
    hipLaunchKernelGGL(qkv_gemm, dim3(BT / 128, 3 * C_ / 128), dim3(256), 0, stream, xbf, wt, qb, kb, vb);
    hipLaunchKernelGGL(vtrans, dim3(T_ / 64, BH), dim3(256), 0, stream, vb, vtb);
    hipLaunchKernelGGL(attn, dim3(16, BH), dim3(256), 0, stream, qb, kb, vtb, attb);
    hipLaunchKernelGGL(out_gemm, dim3(BT / 128, C_ / 128), dim3(256), 0, stream, attb, wobf, bo, out);
}

// Round 7
// 256.628 us; speedup vs baseline: 1.9917x; 1.1854x over previous
//
#include <hip/hip_runtime.h>
#include <hip/hip_bf16.h>
#include <math.h>

#define B_ 4
#define T_ 2048
#define C_ 1024
#define H_ 16
#define D_ 64
#define BT (B_*T_)
#define BH (B_*H_)

typedef __bf16 bf16x8 __attribute__((ext_vector_type(8)));
typedef __bf16 bf16x4 __attribute__((ext_vector_type(4)));
typedef float f32x4 __attribute__((ext_vector_type(4)));
typedef unsigned short u16;
typedef u16 u16x8 __attribute__((ext_vector_type(8)));

// async global->LDS, 16B/lane; LDS dest = wave-uniform base + lane*16
#define GLL(g, l) __builtin_amdgcn_global_load_lds( \
    (const __attribute__((address_space(1))) unsigned int*)(g), \
    (__attribute__((address_space(3))) unsigned int*)(l), 16, 0, 0)

__device__ __forceinline__ u16 f2b(float f) {
    union { float f; unsigned u; } v; v.f = f;
    unsigned r = v.u + 0x7fffu + ((v.u >> 16) & 1u);
    return (u16)(r >> 16);
}

// ---------------- cast fp32 -> bf16 (n divisible by 1024) ----------------
__global__ __launch_bounds__(256) void cast_f32_bf16(const float* __restrict__ in,
                                                     u16* __restrict__ out) {
    int g = blockIdx.x * 256 + threadIdx.x;
    float4 x = ((const float4*)in)[g];
    ushort4 o;
    o.x = f2b(x.x); o.y = f2b(x.y); o.z = f2b(x.z); o.w = f2b(x.w);
    ((ushort4*)out)[g] = o;
}

// ------------- Wq/Wk/Wv [H,C,D] fp32 -> [3,H,D,C] bf16 (= [3072,1024]) ----
__global__ __launch_bounds__(256) void transpose_w(const float* __restrict__ Wq,
                                                   const float* __restrict__ Wk,
                                                   const float* __restrict__ Wv,
                                                   u16* __restrict__ out) {
    __shared__ u16 lds[64][72];
    int cb = blockIdx.x, h = blockIdx.y, w = blockIdx.z;
    const float* W = (w == 0) ? Wq : (w == 1) ? Wk : Wv;
    int tid = threadIdx.x;
    int c0 = cb * 64;
    {
        int col = (tid & 15) * 4;
        for (int cc = 0; cc < 4; ++cc) {
            int r = (tid >> 4) + cc * 16;
            float4 x = *(const float4*)&W[(size_t)(h * C_ + c0 + r) * D_ + col];
            lds[r][col + 0] = f2b(x.x); lds[r][col + 1] = f2b(x.y);
            lds[r][col + 2] = f2b(x.z); lds[r][col + 3] = f2b(x.w);
        }
    }
    __syncthreads();
    {
        int tcol = (tid & 7) * 8;
        for (int cc = 0; cc < 2; ++cc) {
            int d = (tid >> 3) + cc * 32;
            u16x8 t;
            for (int j = 0; j < 8; ++j) t[j] = lds[tcol + j][d];
            *(u16x8*)&out[(((size_t)(w * H_ + h) * D_ + d) * C_) + c0 + tcol] = t;
        }
    }
}

// ------- fused QKV GEMM: x[8192,1024] x wt[3072,1024]^T -> q/k/v [BH,T,D] -------
// 128x128 tile; GLL width-16 staging with XOR column swizzle.
__global__ __launch_bounds__(256) void qkv_gemm(const u16* __restrict__ xbf,
                                                const u16* __restrict__ wt,
                                                u16* __restrict__ q, u16* __restrict__ k,
                                                u16* __restrict__ v) {
    __shared__ u16 Al[128][64];
    __shared__ u16 Bl[128][64];
    int mb = blockIdx.x, nb = blockIdx.y;
    int tid = threadIdx.x, wv = tid >> 6, lane = tid & 63, l15 = lane & 15, quad = lane >> 4;
    int rowh = (wv & 1) * 64, colh = (wv >> 1) * 64;
    f32x4 acc[4][4];
    #pragma unroll
    for (int i = 0; i < 4; ++i)
        #pragma unroll
        for (int j = 0; j < 4; ++j) acc[i][j] = (f32x4){0.f, 0.f, 0.f, 0.f};
    int lrow = lane >> 3;                       // 0..7
    int srow = wv * 32 + lrow;
    int scol = (((lane & 7) ^ lrow)) * 8;       // swizzled source column
    const u16* agp = &xbf[(size_t)(mb * 128 + srow) * C_ + scol];
    const u16* bgp = &wt[(size_t)(nb * 128 + srow) * C_ + scol];
    int rsw = l15 & 7;                          // read-side swizzle key
    for (int k0 = 0; k0 < C_; k0 += 64) {
        #pragma unroll
        for (int j = 0; j < 4; ++j) {
            GLL(agp + (size_t)(j * 8) * C_ + k0, &Al[wv * 32 + j * 8][0]);
            GLL(bgp + (size_t)(j * 8) * C_ + k0, &Bl[wv * 32 + j * 8][0]);
        }
        __syncthreads();
        #pragma unroll
        for (int ks = 0; ks < 2; ++ks) {
            int cbl = (((ks << 2) | quad) ^ rsw) * 8;
            bf16x8 af[4], bf[4];
            #pragma unroll
            for (int mt = 0; mt < 4; ++mt)
                af[mt] = *(const bf16x8*)&Al[rowh + mt * 16 + l15][cbl];
            #pragma unroll
            for (int nt = 0; nt < 4; ++nt)
                bf[nt] = *(const bf16x8*)&Bl[colh + nt * 16 + l15][cbl];
            #pragma unroll
            for (int mt = 0; mt < 4; ++mt)
                #pragma unroll
                for (int nt = 0; nt < 4; ++nt)
                    acc[mt][nt] = __builtin_amdgcn_mfma_f32_16x16x32_bf16(af[mt], bf[nt], acc[mt][nt], 0, 0, 0);
        }
        __syncthreads();
    }
    #pragma unroll
    for (int nt = 0; nt < 4; ++nt) {
        int n0 = nb * 128 + colh + nt * 16;
        int wsel = n0 >> 10, hh = (n0 >> 6) & 15, d0 = n0 & 63;
        u16* op = (wsel == 0) ? q : (wsel == 1) ? k : v;
        #pragma unroll
        for (int mt = 0; mt < 4; ++mt)
            #pragma unroll
            for (int r = 0; r < 4; ++r) {
                int m = mb * 128 + rowh + mt * 16 + quad * 4 + r;
                int bb = m >> 11, tt = m & (T_ - 1);
                op[((size_t)(bb * H_ + hh) * T_ + tt) * D_ + d0 + l15] = f2b(acc[mt][nt][r]);
            }
    }
}

// ---------------- V [BH,T,D] -> Vt [BH,D,T] (bf16) ----------------
__global__ __launch_bounds__(256) void vtrans(const u16* __restrict__ v, u16* __restrict__ vt) {
    __shared__ u16 lds[64][72];
    int tb = blockIdx.x, bh = blockIdx.y;
    int t0 = tb * 64, tid = threadIdx.x;
    int col = (tid & 7) * 8;
    for (int cc = 0; cc < 2; ++cc) {
        int r = (tid >> 3) + cc * 32;
        *(u16x8*)&lds[r][col] = *(const u16x8*)&v[((size_t)bh * T_ + t0 + r) * D_ + col];
    }
    __syncthreads();
    for (int cc = 0; cc < 2; ++cc) {
        int d = (tid >> 3) + cc * 32;
        u16x8 t;
        for (int j = 0; j < 8; ++j) t[j] = lds[col + j][d];
        *(u16x8*)&vt[((size_t)bh * D_ + d) * T_ + t0 + col] = t;
    }
}

// -------- flash attention v3: block-cooperative LDS K/V, S^T/O^T form -----
// Block = 4 waves x 32 Q rows = 128-row chunk; grid (8,BH) chunk pair
// (p,15-p) -> uniform 34 tiles/block. K/V tiles staged via GLL (each wave
// 16 rows), double-buffered, prefetched one tile ahead; ONE barrier/tile.
// XOR column swizzle makes ds_read_b128 frag reads conflict-free.
__global__ __launch_bounds__(256, 2) void attn(const u16* __restrict__ q, const u16* __restrict__ kk,
                                               const u16* __restrict__ vt, u16* __restrict__ att) {
    __shared__ u16 Kl[2][64][64];
    __shared__ u16 Vl[2][64][64];
    __shared__ u16 Pl[4][32][72];
    int p = blockIdx.x, bh = blockIdx.y;
    int b = bh >> 4, h = bh & 15;
    int tid = threadIdx.x, wid = tid >> 6, lane = tid & 63, l15 = lane & 15, quad = lane >> 4;
    const float scale2 = 0.04508422f;  // C^-0.5 * log2(e)
    const u16* qbase = q + (size_t)bh * T_ * D_;
    const u16* kbase = kk + (size_t)bh * T_ * D_;
    const u16* vbase = vt + (size_t)bh * D_ * T_;
    u16* pw = &Pl[wid][0][0];
    bf16x8 ones;
    #pragma unroll
    for (int j = 0; j < 8; ++j) ones[j] = (__bf16)1.0f;
    // staging lane geometry: wave wid stages rows [wid*16, wid*16+16)
    int r8 = lane >> 3, cbl_st = lane & 7;
    int csrc = ((cbl_st ^ r8)) * 8;            // swizzled source column (elements)
    int strow = wid * 16 + r8;                  // +j*8
    int rsw = l15 & 7;                          // read-side swizzle key

    for (int ci = 0; ci < 2; ++ci) {
        int c = ci ? (15 - p) : p;
        int R0q = c * 128 + wid * 32;
        int ktb = 2 * c + 1;                    // block-level last tile
        int kmax_w = R0q >> 6;                  // wave-level last needed tile
        // Q^T B-frags: B[k=d][n=qrow]
        bf16x8 bq[2][2];
        #pragma unroll
        for (int qt = 0; qt < 2; ++qt)
            #pragma unroll
            for (int kd = 0; kd < 2; ++kd)
                bq[qt][kd] = *(const bf16x8*)&qbase[(size_t)(R0q + qt * 16 + l15) * D_ + kd * 32 + quad * 8];
        f32x4 o[4][2];
        f32x4 lacc[2];
        float m2[2] = {-INFINITY, -INFINITY};
        #pragma unroll
        for (int dt = 0; dt < 4; ++dt)
            #pragma unroll
            for (int qt = 0; qt < 2; ++qt) o[dt][qt] = (f32x4){0.f, 0.f, 0.f, 0.f};
        lacc[0] = (f32x4){0.f, 0.f, 0.f, 0.f};
        lacc[1] = (f32x4){0.f, 0.f, 0.f, 0.f};
        // stage tile 0 into buffer 0
        #pragma unroll
        for (int j = 0; j < 2; ++j) {
            GLL(kbase + (size_t)(strow + j * 8) * D_ + csrc, &Kl[0][wid * 16 + j * 8][0]);
            GLL(vbase + (size_t)(strow + j * 8) * T_ + csrc, &Vl[0][wid * 16 + j * 8][0]);
        }
        __syncthreads();
        for (int kt = 0; kt <= ktb; ++kt) {
            int cur = kt & 1;
            if (kt < ktb) {  // prefetch next tile into the other buffer
                int kn = (kt + 1) * 64;
                #pragma unroll
                for (int j = 0; j < 2; ++j) {
                    GLL(kbase + (size_t)(kn + strow + j * 8) * D_ + csrc, &Kl[cur ^ 1][wid * 16 + j * 8][0]);
                    GLL(vbase + (size_t)(strow + j * 8) * T_ + kn + csrc, &Vl[cur ^ 1][wid * 16 + j * 8][0]);
                }
            }
            if (kt <= kmax_w) {
                int k0 = kt * 64;
                // S^T = K . Q^T : C col = qrow(l15), row = kv(quad*4+r)
                f32x4 sS[4][2];
                #pragma unroll
                for (int kvt = 0; kvt < 4; ++kvt)
                    #pragma unroll
                    for (int qt = 0; qt < 2; ++qt) sS[kvt][qt] = (f32x4){0.f, 0.f, 0.f, 0.f};
                #pragma unroll
                for (int kd = 0; kd < 2; ++kd) {
                    int cblk = (((kd << 2) | quad) ^ rsw) * 8;
                    bf16x8 akf[4];
                    #pragma unroll
                    for (int kvt = 0; kvt < 4; ++kvt)
                        akf[kvt] = *(const bf16x8*)&Kl[cur][kvt * 16 + l15][cblk];
                    #pragma unroll
                    for (int kvt = 0; kvt < 4; ++kvt)
                        #pragma unroll
                        for (int qt = 0; qt < 2; ++qt)
                            sS[kvt][qt] = __builtin_amdgcn_mfma_f32_16x16x32_bf16(akf[kvt], bq[qt][kd], sS[kvt][qt], 0, 0, 0);
                }
                if (kt == kmax_w) {  // causal mask, diagonal tile only
                    #pragma unroll
                    for (int qt = 0; qt < 2; ++qt) {
                        int qabs = R0q + qt * 16 + l15;
                        #pragma unroll
                        for (int kvt = 0; kvt < 4; ++kvt) {
                            int kvb = k0 + kvt * 16 + quad * 4;
                            #pragma unroll
                            for (int r = 0; r < 4; ++r)
                                if (kvb + r > qabs) sS[kvt][qt][r] = -INFINITY;
                        }
                    }
                }
                // online softmax (exp2 domain): 16 in-lane fmax + 2 shfl per qt
                float alpha[2];
                #pragma unroll
                for (int qt = 0; qt < 2; ++qt) {
                    float vm = sS[0][qt][0];
                    #pragma unroll
                    for (int kvt = 0; kvt < 4; ++kvt)
                        #pragma unroll
                        for (int r = 0; r < 4; ++r) vm = fmaxf(vm, sS[kvt][qt][r]);
                    vm = fmaxf(vm, __shfl_xor(vm, 16));
                    vm = fmaxf(vm, __shfl_xor(vm, 32));
                    float mn = fmaxf(m2[qt], vm * scale2);
                    alpha[qt] = __builtin_amdgcn_exp2f(m2[qt] - mn);
                    m2[qt] = mn;
                }
                #pragma unroll
                for (int kvt = 0; kvt < 4; ++kvt)
                    #pragma unroll
                    for (int qt = 0; qt < 2; ++qt)
                        #pragma unroll
                        for (int r = 0; r < 4; ++r)
                            sS[kvt][qt][r] = __builtin_amdgcn_exp2f(fmaf(sS[kvt][qt][r], scale2, -m2[qt]));
                #pragma unroll
                for (int dt = 0; dt < 4; ++dt)
                    #pragma unroll
                    for (int qt = 0; qt < 2; ++qt)
                        #pragma unroll
                        for (int r = 0; r < 4; ++r) o[dt][qt][r] *= alpha[qt];
                #pragma unroll
                for (int qt = 0; qt < 2; ++qt)
                    #pragma unroll
                    for (int r = 0; r < 4; ++r) lacc[qt][r] *= alpha[qt];
                // P -> wave-private LDS: P[qrow][kv] (bf16)
                #pragma unroll
                for (int qt = 0; qt < 2; ++qt)
                    #pragma unroll
                    for (int kvt = 0; kvt < 4; ++kvt) {
                        bf16x4 w;
                        #pragma unroll
                        for (int r = 0; r < 4; ++r) w[r] = (__bf16)sS[kvt][qt][r];
                        *(bf16x4*)&pw[(qt * 16 + l15) * 72 + kvt * 16 + quad * 4] = w;
                    }
                // O^T += V^T . P^T ; l += ones . P^T
                #pragma unroll
                for (int ks = 0; ks < 2; ++ks) {
                    int cblk = (((ks << 2) | quad) ^ rsw) * 8;
                    bf16x8 avf[4];
                    #pragma unroll
                    for (int dt = 0; dt < 4; ++dt)
                        avf[dt] = *(const bf16x8*)&Vl[cur][dt * 16 + l15][cblk];
                    #pragma unroll
                    for (int qt = 0; qt < 2; ++qt) {
                        bf16x8 bp = *(const bf16x8*)&pw[(qt * 16 + l15) * 72 + ks * 32 + quad * 8];
                        #pragma unroll
                        for (int dt = 0; dt < 4; ++dt)
                            o[dt][qt] = __builtin_amdgcn_mfma_f32_16x16x32_bf16(avf[dt], bp, o[dt][qt], 0, 0, 0);
                        lacc[qt] = __builtin_amdgcn_mfma_f32_16x16x32_bf16(ones, bp, lacc[qt], 0, 0, 0);
                    }
                }
            }
            __syncthreads();   // staging for kt+1 drained; buffers safe to swap
        }
        // epilogue: O^T[d][qrow] / l -> att[b*T+qrow][h*64+d]
        #pragma unroll
        for (int qt = 0; qt < 2; ++qt) {
            float rl = __builtin_amdgcn_rcpf(lacc[qt][0]);
            int qabs = R0q + qt * 16 + l15;
            #pragma unroll
            for (int dt = 0; dt < 4; ++dt) {
                bf16x4 w;
                #pragma unroll
                for (int r = 0; r < 4; ++r) w[r] = (__bf16)(o[dt][qt][r] * rl);
                *(bf16x4*)&att[(size_t)(b * T_ + qabs) * C_ + h * 64 + dt * 16 + quad * 4] = w;
            }
        }
    }
}

// ------ out proj: att[8192,1024] x wo[1024,1024]^T + bo -> fp32 out -------
__global__ __launch_bounds__(256) void out_gemm(const u16* __restrict__ att,
                                                const u16* __restrict__ wo,
                                                const float* __restrict__ bo,
                                                float* __restrict__ out) {
    __shared__ u16 Al[128][64];
    __shared__ u16 Bl[128][64];
    int mb = blockIdx.x, nb = blockIdx.y;
    int tid = threadIdx.x, wv = tid >> 6, lane = tid & 63, l15 = lane & 15, quad = lane >> 4;
    int rowh = (wv & 1) * 64, colh = (wv >> 1) * 64;
    f32x4 acc[4][4];
    #pragma unroll
    for (int i = 0; i < 4; ++i)
        #pragma unroll
        for (int j = 0; j < 4; ++j) acc[i][j] = (f32x4){0.f, 0.f, 0.f, 0.f};
    int lrow = lane >> 3;
    int srow = wv * 32 + lrow;
    int scol = (((lane & 7) ^ lrow)) * 8;
    const u16* agp = &att[(size_t)(mb * 128 + srow) * C_ + scol];
    const u16* bgp = &wo[(size_t)(nb * 128 + srow) * C_ + scol];
    int rsw = l15 & 7;
    for (int k0 = 0; k0 < C_; k0 += 64) {
        #pragma unroll
        for (int j = 0; j < 4; ++j) {
            GLL(agp + (size_t)(j * 8) * C_ + k0, &Al[wv * 32 + j * 8][0]);
            GLL(bgp + (size_t)(j * 8) * C_ + k0, &Bl[wv * 32 + j * 8][0]);
        }
        __syncthreads();
        #pragma unroll
        for (int ks = 0; ks < 2; ++ks) {
            int cbl = (((ks << 2) | quad) ^ rsw) * 8;
            bf16x8 af[4], bf[4];
            #pragma unroll
            for (int mt = 0; mt < 4; ++mt)
                af[mt] = *(const bf16x8*)&Al[rowh + mt * 16 + l15][cbl];
            #pragma unroll
            for (int nt = 0; nt < 4; ++nt)
                bf[nt] = *(const bf16x8*)&Bl[colh + nt * 16 + l15][cbl];
            #pragma unroll
            for (int mt = 0; mt < 4; ++mt)
                #pragma unroll
                for (int nt = 0; nt < 4; ++nt)
                    acc[mt][nt] = __builtin_amdgcn_mfma_f32_16x16x32_bf16(af[mt], bf[nt], acc[mt][nt], 0, 0, 0);
        }
        __syncthreads();
    }
    #pragma unroll
    for (int nt = 0; nt < 4; ++nt) {
        int n = nb * 128 + colh + nt * 16 + l15;
        float bias = bo[n];
        #pragma unroll
        for (int mt = 0; mt < 4; ++mt)
            #pragma unroll
            for (int r = 0; r < 4; ++r) {
                int m = mb * 128 + rowh + mt * 16 + quad * 4 + r;
                out[(size_t)m * C_ + n] = acc[mt][nt][r] + bias;
            }
    }
}

extern "C" void kernel_launch(void* const* d_in, const int* in_sizes, int n_in,
                              void* d_out, int out_size, void* d_ws, size_t ws_size,
                              hipStream_t stream) {
    const float* x  = (const float*)d_in[0];
    const float* Wq = (const float*)d_in[1];
    const float* Wk = (const float*)d_in[2];
    const float* Wv = (const float*)d_in[3];
    const float* Wo = (const float*)d_in[4];
    const float* bo = (const float*)d_in[5];
    float* out = (float*)d_out;
    char* ws = (char*)d_ws;
    u16* xbf  = (u16*)(ws + (size_t)0);           // 16 MB  x bf16 [8192,1024]
    u16* wt   = (u16*)(ws + ((size_t)16 << 20));  //  6 MB  W qkv [3072,1024] bf16
    u16* wobf = (u16*)(ws + ((size_t)22 << 20));  //  2 MB  Wo bf16 [1024,1024]
    u16* qb   = (u16*)(ws + ((size_t)24 << 20));  // 16 MB  q [BH,T,D]
    u16* kb   = (u16*)(ws + ((size_t)40 << 20));  // 16 MB  k [BH,T,D]
    u16* vb   = (u16*)(ws + ((size_t)56 << 20));  // 16 MB  v [BH,T,D]
    u16* vtb  = (u16*)(ws + ((size_t)72 << 20));  // 16 MB  v^T [BH,D,T]
    u16* attb = (u16*)(ws + ((size_t)88 << 20));  // 16 MB  att out [B*T,C]

    hipLaunchKernelGGL(cast_f32_bf16, dim3(BT * C_ / 1024), dim3(256), 0, stream, x, xbf);
    hipLaunchKernelGGL(cast_f32_bf16, dim3(C_ * C_ / 1024), dim3(256), 0, stream, Wo, wobf);
    hipLaunchKernelGGL(transpose_w, dim3(C_ / 64, H_, 3), dim3(256), 0, stream, Wq, Wk, Wv, wt);
    hipLaunchKernelGGL(qkv_gemm, dim3(BT / 128, 3 * C_ / 128), dim3(256), 0, stream, xbf, wt, qb, kb, vb);
    hipLaunchKernelGGL(vtrans, dim3(T_ / 64, BH), dim3(256), 0, stream, vb, vtb);
    hipLaunchKernelGGL(attn, dim3(8, BH), dim3(256), 0, stream, qb, kb, vtb, attb);
    hipLaunchKernelGGL(out_gemm, dim3(BT / 128, C_ / 128), dim3(256), 0, stream, attb, wobf, bo, out);
}

// Round 8
// 246.985 us; speedup vs baseline: 2.0695x; 1.0390x over previous
//
#include <hip/hip_runtime.h>
#include <hip/hip_bf16.h>
#include <math.h>

#define B_ 4
#define T_ 2048
#define C_ 1024
#define H_ 16
#define D_ 64
#define BT (B_*T_)
#define BH (B_*H_)

typedef __bf16 bf16x8 __attribute__((ext_vector_type(8)));
typedef __bf16 bf16x4 __attribute__((ext_vector_type(4)));
typedef float f32x4 __attribute__((ext_vector_type(4)));
typedef unsigned short u16;
typedef u16 u16x8 __attribute__((ext_vector_type(8)));

// async global->LDS, 16B/lane; LDS dest = wave-uniform base + lane*16
#define GLL(g, l) __builtin_amdgcn_global_load_lds( \
    (const __attribute__((address_space(1))) unsigned int*)(g), \
    (__attribute__((address_space(3))) unsigned int*)(l), 16, 0, 0)

#define SCALE2 0.04508422f  // C^-0.5 * log2(e), folded into Wq

__device__ __forceinline__ u16 f2b(float f) {
    union { float f; unsigned u; } v; v.f = f;
    unsigned r = v.u + 0x7fffu + ((v.u >> 16) & 1u);
    return (u16)(r >> 16);
}

// ---------------- cast fp32 -> bf16 (n divisible by 1024) ----------------
__global__ __launch_bounds__(256) void cast_f32_bf16(const float* __restrict__ in,
                                                     u16* __restrict__ out) {
    int g = blockIdx.x * 256 + threadIdx.x;
    float4 x = ((const float4*)in)[g];
    ushort4 o;
    o.x = f2b(x.x); o.y = f2b(x.y); o.z = f2b(x.z); o.w = f2b(x.w);
    ((ushort4*)out)[g] = o;
}

// ------------- Wq/Wk/Wv [H,C,D] fp32 -> [3,H,D,C] bf16 (= [3072,1024]) ----
// Wq is pre-scaled by C^-0.5*log2(e) so attention scores exit QK^T already
// in the exp2 domain (saves 32 v_fma per tile in the attn softmax).
__global__ __launch_bounds__(256) void transpose_w(const float* __restrict__ Wq,
                                                   const float* __restrict__ Wk,
                                                   const float* __restrict__ Wv,
                                                   u16* __restrict__ out) {
    __shared__ u16 lds[64][72];
    int cb = blockIdx.x, h = blockIdx.y, w = blockIdx.z;
    const float* W = (w == 0) ? Wq : (w == 1) ? Wk : Wv;
    float sc = (w == 0) ? SCALE2 : 1.0f;
    int tid = threadIdx.x;
    int c0 = cb * 64;
    {
        int col = (tid & 15) * 4;
        for (int cc = 0; cc < 4; ++cc) {
            int r = (tid >> 4) + cc * 16;
            float4 x = *(const float4*)&W[(size_t)(h * C_ + c0 + r) * D_ + col];
            lds[r][col + 0] = f2b(x.x * sc); lds[r][col + 1] = f2b(x.y * sc);
            lds[r][col + 2] = f2b(x.z * sc); lds[r][col + 3] = f2b(x.w * sc);
        }
    }
    __syncthreads();
    {
        int tcol = (tid & 7) * 8;
        for (int cc = 0; cc < 2; ++cc) {
            int d = (tid >> 3) + cc * 32;
            u16x8 t;
            for (int j = 0; j < 8; ++j) t[j] = lds[tcol + j][d];
            *(u16x8*)&out[(((size_t)(w * H_ + h) * D_ + d) * C_) + c0 + tcol] = t;
        }
    }
}

// ------- fused QKV GEMM: x[8192,1024] x wt[3072,1024]^T -> q/k/v [BH,T,D] -------
// 128x128 tile; GLL width-16 staging with XOR column swizzle.
__global__ __launch_bounds__(256) void qkv_gemm(const u16* __restrict__ xbf,
                                                const u16* __restrict__ wt,
                                                u16* __restrict__ q, u16* __restrict__ k,
                                                u16* __restrict__ v) {
    __shared__ u16 Al[128][64];
    __shared__ u16 Bl[128][64];
    int mb = blockIdx.x, nb = blockIdx.y;
    int tid = threadIdx.x, wv = tid >> 6, lane = tid & 63, l15 = lane & 15, quad = lane >> 4;
    int rowh = (wv & 1) * 64, colh = (wv >> 1) * 64;
    f32x4 acc[4][4];
    #pragma unroll
    for (int i = 0; i < 4; ++i)
        #pragma unroll
        for (int j = 0; j < 4; ++j) acc[i][j] = (f32x4){0.f, 0.f, 0.f, 0.f};
    int lrow = lane >> 3;                       // 0..7
    int srow = wv * 32 + lrow;
    int scol = (((lane & 7) ^ lrow)) * 8;       // swizzled source column
    const u16* agp = &xbf[(size_t)(mb * 128 + srow) * C_ + scol];
    const u16* bgp = &wt[(size_t)(nb * 128 + srow) * C_ + scol];
    int rsw = l15 & 7;                          // read-side swizzle key
    for (int k0 = 0; k0 < C_; k0 += 64) {
        #pragma unroll
        for (int j = 0; j < 4; ++j) {
            GLL(agp + (size_t)(j * 8) * C_ + k0, &Al[wv * 32 + j * 8][0]);
            GLL(bgp + (size_t)(j * 8) * C_ + k0, &Bl[wv * 32 + j * 8][0]);
        }
        __syncthreads();
        #pragma unroll
        for (int ks = 0; ks < 2; ++ks) {
            int cbl = (((ks << 2) | quad) ^ rsw) * 8;
            bf16x8 af[4], bf[4];
            #pragma unroll
            for (int mt = 0; mt < 4; ++mt)
                af[mt] = *(const bf16x8*)&Al[rowh + mt * 16 + l15][cbl];
            #pragma unroll
            for (int nt = 0; nt < 4; ++nt)
                bf[nt] = *(const bf16x8*)&Bl[colh + nt * 16 + l15][cbl];
            #pragma unroll
            for (int mt = 0; mt < 4; ++mt)
                #pragma unroll
                for (int nt = 0; nt < 4; ++nt)
                    acc[mt][nt] = __builtin_amdgcn_mfma_f32_16x16x32_bf16(af[mt], bf[nt], acc[mt][nt], 0, 0, 0);
        }
        __syncthreads();
    }
    #pragma unroll
    for (int nt = 0; nt < 4; ++nt) {
        int n0 = nb * 128 + colh + nt * 16;
        int wsel = n0 >> 10, hh = (n0 >> 6) & 15, d0 = n0 & 63;
        u16* op = (wsel == 0) ? q : (wsel == 1) ? k : v;
        #pragma unroll
        for (int mt = 0; mt < 4; ++mt)
            #pragma unroll
            for (int r = 0; r < 4; ++r) {
                int m = mb * 128 + rowh + mt * 16 + quad * 4 + r;
                int bb = m >> 11, tt = m & (T_ - 1);
                op[((size_t)(bb * H_ + hh) * T_ + tt) * D_ + d0 + l15] = f2b(acc[mt][nt][r]);
            }
    }
}

// ---------------- V [BH,T,D] -> Vt [BH,D,T] (bf16) ----------------
__global__ __launch_bounds__(256) void vtrans(const u16* __restrict__ v, u16* __restrict__ vt) {
    __shared__ u16 lds[64][72];
    int tb = blockIdx.x, bh = blockIdx.y;
    int t0 = tb * 64, tid = threadIdx.x;
    int col = (tid & 7) * 8;
    for (int cc = 0; cc < 2; ++cc) {
        int r = (tid >> 3) + cc * 32;
        *(u16x8*)&lds[r][col] = *(const u16x8*)&v[((size_t)bh * T_ + t0 + r) * D_ + col];
    }
    __syncthreads();
    for (int cc = 0; cc < 2; ++cc) {
        int d = (tid >> 3) + cc * 32;
        u16x8 t;
        for (int j = 0; j < 8; ++j) t[j] = lds[col + j][d];
        *(u16x8*)&vt[((size_t)bh * D_ + d) * T_ + t0 + col] = t;
    }
}

// -------- flash attention v4: one 128-row chunk per block -----------------
// Grid (BH, 16): gridDim.x=64 (multiple of 8) => linear id % 8 == bh % 8,
// so all 16 chunk-blocks of a head land on ONE XCD -> K/V hit that XCD's L2.
// c = 15 - blockIdx.y: heavy chunks dispatch first; 1024 blocks = 4 rounds
// backfill the causal imbalance. 3 blocks/CU (LDS 50 KB), 12 waves/CU.
// K/V staged cooperatively via GLL, double-buffered, ONE barrier per tile.
__global__ __launch_bounds__(256, 2) void attn(const u16* __restrict__ q, const u16* __restrict__ kk,
                                               const u16* __restrict__ vt, u16* __restrict__ att) {
    __shared__ u16 Kl[2][64][64];
    __shared__ u16 Vl[2][64][64];
    __shared__ u16 Pl[4][32][72];
    int bh = blockIdx.x, c = 15 - blockIdx.y;
    int b = bh >> 4, h = bh & 15;
    int tid = threadIdx.x, wid = tid >> 6, lane = tid & 63, l15 = lane & 15, quad = lane >> 4;
    const u16* qbase = q + (size_t)bh * T_ * D_;
    const u16* kbase = kk + (size_t)bh * T_ * D_;
    const u16* vbase = vt + (size_t)bh * D_ * T_;
    u16* pw = &Pl[wid][0][0];
    bf16x8 ones;
    #pragma unroll
    for (int j = 0; j < 8; ++j) ones[j] = (__bf16)1.0f;
    // staging lane geometry: wave wid stages rows [wid*16, wid*16+16)
    int r8 = lane >> 3, cbl_st = lane & 7;
    int csrc = ((cbl_st ^ r8)) * 8;            // swizzled source column (elements)
    int strow = wid * 16 + r8;                  // +j*8
    int rsw = l15 & 7;                          // read-side swizzle key

    int R0q = c * 128 + wid * 32;
    int ktb = 2 * c + 1;                        // block-level last tile
    int kmax_w = R0q >> 6;                      // wave-level last needed tile
    // Q^T B-frags: B[k=d][n=qrow]  (q pre-scaled by C^-0.5*log2e)
    bf16x8 bq[2][2];
    #pragma unroll
    for (int qt = 0; qt < 2; ++qt)
        #pragma unroll
        for (int kd = 0; kd < 2; ++kd)
            bq[qt][kd] = *(const bf16x8*)&qbase[(size_t)(R0q + qt * 16 + l15) * D_ + kd * 32 + quad * 8];
    f32x4 o[4][2];
    f32x4 lacc[2];
    float m2[2] = {-INFINITY, -INFINITY};
    #pragma unroll
    for (int dt = 0; dt < 4; ++dt)
        #pragma unroll
        for (int qt = 0; qt < 2; ++qt) o[dt][qt] = (f32x4){0.f, 0.f, 0.f, 0.f};
    lacc[0] = (f32x4){0.f, 0.f, 0.f, 0.f};
    lacc[1] = (f32x4){0.f, 0.f, 0.f, 0.f};
    // stage tile 0 into buffer 0
    #pragma unroll
    for (int j = 0; j < 2; ++j) {
        GLL(kbase + (size_t)(strow + j * 8) * D_ + csrc, &Kl[0][wid * 16 + j * 8][0]);
        GLL(vbase + (size_t)(strow + j * 8) * T_ + csrc, &Vl[0][wid * 16 + j * 8][0]);
    }
    __syncthreads();
    for (int kt = 0; kt <= ktb; ++kt) {
        int cur = kt & 1;
        if (kt < ktb) {  // prefetch next tile into the other buffer
            int kn = (kt + 1) * 64;
            #pragma unroll
            for (int j = 0; j < 2; ++j) {
                GLL(kbase + (size_t)(kn + strow + j * 8) * D_ + csrc, &Kl[cur ^ 1][wid * 16 + j * 8][0]);
                GLL(vbase + (size_t)(strow + j * 8) * T_ + kn + csrc, &Vl[cur ^ 1][wid * 16 + j * 8][0]);
            }
        }
        if (kt <= kmax_w) {
            int k0 = kt * 64;
            // S^T = K . Q^T : C col = qrow(l15), row = kv(quad*4+r); exp2 domain
            f32x4 sS[4][2];
            #pragma unroll
            for (int kvt = 0; kvt < 4; ++kvt)
                #pragma unroll
                for (int qt = 0; qt < 2; ++qt) sS[kvt][qt] = (f32x4){0.f, 0.f, 0.f, 0.f};
            #pragma unroll
            for (int kd = 0; kd < 2; ++kd) {
                int cblk = (((kd << 2) | quad) ^ rsw) * 8;
                bf16x8 akf[4];
                #pragma unroll
                for (int kvt = 0; kvt < 4; ++kvt)
                    akf[kvt] = *(const bf16x8*)&Kl[cur][kvt * 16 + l15][cblk];
                #pragma unroll
                for (int kvt = 0; kvt < 4; ++kvt)
                    #pragma unroll
                    for (int qt = 0; qt < 2; ++qt)
                        sS[kvt][qt] = __builtin_amdgcn_mfma_f32_16x16x32_bf16(akf[kvt], bq[qt][kd], sS[kvt][qt], 0, 0, 0);
            }
            if (kt == kmax_w) {  // causal mask, diagonal tile only
                #pragma unroll
                for (int qt = 0; qt < 2; ++qt) {
                    int qabs = R0q + qt * 16 + l15;
                    #pragma unroll
                    for (int kvt = 0; kvt < 4; ++kvt) {
                        int kvb = k0 + kvt * 16 + quad * 4;
                        #pragma unroll
                        for (int r = 0; r < 4; ++r)
                            if (kvb + r > qabs) sS[kvt][qt][r] = -INFINITY;
                    }
                }
            }
            // online softmax (exp2 domain, pre-scaled): 16 in-lane fmax + 2 shfl
            float alpha[2];
            #pragma unroll
            for (int qt = 0; qt < 2; ++qt) {
                float vm = sS[0][qt][0];
                #pragma unroll
                for (int kvt = 0; kvt < 4; ++kvt)
                    #pragma unroll
                    for (int r = 0; r < 4; ++r) vm = fmaxf(vm, sS[kvt][qt][r]);
                vm = fmaxf(vm, __shfl_xor(vm, 16));
                vm = fmaxf(vm, __shfl_xor(vm, 32));
                float mn = fmaxf(m2[qt], vm);
                alpha[qt] = __builtin_amdgcn_exp2f(m2[qt] - mn);
                m2[qt] = mn;
            }
            #pragma unroll
            for (int kvt = 0; kvt < 4; ++kvt)
                #pragma unroll
                for (int qt = 0; qt < 2; ++qt)
                    #pragma unroll
                    for (int r = 0; r < 4; ++r)
                        sS[kvt][qt][r] = __builtin_amdgcn_exp2f(sS[kvt][qt][r] - m2[qt]);
            #pragma unroll
            for (int dt = 0; dt < 4; ++dt)
                #pragma unroll
                for (int qt = 0; qt < 2; ++qt)
                    #pragma unroll
                    for (int r = 0; r < 4; ++r) o[dt][qt][r] *= alpha[qt];
            #pragma unroll
            for (int qt = 0; qt < 2; ++qt)
                #pragma unroll
                for (int r = 0; r < 4; ++r) lacc[qt][r] *= alpha[qt];
            // P -> wave-private LDS: P[qrow][kv] (bf16)
            #pragma unroll
            for (int qt = 0; qt < 2; ++qt)
                #pragma unroll
                for (int kvt = 0; kvt < 4; ++kvt) {
                    bf16x4 w;
                    #pragma unroll
                    for (int r = 0; r < 4; ++r) w[r] = (__bf16)sS[kvt][qt][r];
                    *(bf16x4*)&pw[(qt * 16 + l15) * 72 + kvt * 16 + quad * 4] = w;
                }
            // O^T += V^T . P^T ; l += ones . P^T
            #pragma unroll
            for (int ks = 0; ks < 2; ++ks) {
                int cblk = (((ks << 2) | quad) ^ rsw) * 8;
                bf16x8 avf[4];
                #pragma unroll
                for (int dt = 0; dt < 4; ++dt)
                    avf[dt] = *(const bf16x8*)&Vl[cur][dt * 16 + l15][cblk];
                #pragma unroll
                for (int qt = 0; qt < 2; ++qt) {
                    bf16x8 bp = *(const bf16x8*)&pw[(qt * 16 + l15) * 72 + ks * 32 + quad * 8];
                    #pragma unroll
                    for (int dt = 0; dt < 4; ++dt)
                        o[dt][qt] = __builtin_amdgcn_mfma_f32_16x16x32_bf16(avf[dt], bp, o[dt][qt], 0, 0, 0);
                    lacc[qt] = __builtin_amdgcn_mfma_f32_16x16x32_bf16(ones, bp, lacc[qt], 0, 0, 0);
                }
            }
        }
        __syncthreads();   // staging for kt+1 drained; buffers safe to swap
    }
    // epilogue: O^T[d][qrow] / l -> att[b*T+qrow][h*64+d]
    #pragma unroll
    for (int qt = 0; qt < 2; ++qt) {
        float rl = __builtin_amdgcn_rcpf(lacc[qt][0]);
        int qabs = R0q + qt * 16 + l15;
        #pragma unroll
        for (int dt = 0; dt < 4; ++dt) {
            bf16x4 w;
            #pragma unroll
            for (int r = 0; r < 4; ++r) w[r] = (__bf16)(o[dt][qt][r] * rl);
            *(bf16x4*)&att[(size_t)(b * T_ + qabs) * C_ + h * 64 + dt * 16 + quad * 4] = w;
        }
    }
}

// ------ out proj: att[8192,1024] x wo[1024,1024]^T + bo -> fp32 out -------
__global__ __launch_bounds__(256) void out_gemm(const u16* __restrict__ att,
                                                const u16* __restrict__ wo,
                                                const float* __restrict__ bo,
                                                float* __restrict__ out) {
    __shared__ u16 Al[128][64];
    __shared__ u16 Bl[128][64];
    int mb = blockIdx.x, nb = blockIdx.y;
    int tid = threadIdx.x, wv = tid >> 6, lane = tid & 63, l15 = lane & 15, quad = lane >> 4;
    int rowh = (wv & 1) * 64, colh = (wv >> 1) * 64;
    f32x4 acc[4][4];
    #pragma unroll
    for (int i = 0; i < 4; ++i)
        #pragma unroll
        for (int j = 0; j < 4; ++j) acc[i][j] = (f32x4){0.f, 0.f, 0.f, 0.f};
    int lrow = lane >> 3;
    int srow = wv * 32 + lrow;
    int scol = (((lane & 7) ^ lrow)) * 8;
    const u16* agp = &att[(size_t)(mb * 128 + srow) * C_ + scol];
    const u16* bgp = &wo[(size_t)(nb * 128 + srow) * C_ + scol];
    int rsw = l15 & 7;
    for (int k0 = 0; k0 < C_; k0 += 64) {
        #pragma unroll
        for (int j = 0; j < 4; ++j) {
            GLL(agp + (size_t)(j * 8) * C_ + k0, &Al[wv * 32 + j * 8][0]);
            GLL(bgp + (size_t)(j * 8) * C_ + k0, &Bl[wv * 32 + j * 8][0]);
        }
        __syncthreads();
        #pragma unroll
        for (int ks = 0; ks < 2; ++ks) {
            int cbl = (((ks << 2) | quad) ^ rsw) * 8;
            bf16x8 af[4], bf[4];
            #pragma unroll
            for (int mt = 0; mt < 4; ++mt)
                af[mt] = *(const bf16x8*)&Al[rowh + mt * 16 + l15][cbl];
            #pragma unroll
            for (int nt = 0; nt < 4; ++nt)
                bf[nt] = *(const bf16x8*)&Bl[colh + nt * 16 + l15][cbl];
            #pragma unroll
            for (int mt = 0; mt < 4; ++mt)
                #pragma unroll
                for (int nt = 0; nt < 4; ++nt)
                    acc[mt][nt] = __builtin_amdgcn_mfma_f32_16x16x32_bf16(af[mt], bf[nt], acc[mt][nt], 0, 0, 0);
        }
        __syncthreads();
    }
    #pragma unroll
    for (int nt = 0; nt < 4; ++nt) {
        int n = nb * 128 + colh + nt * 16 + l15;
        float bias = bo[n];
        #pragma unroll
        for (int mt = 0; mt < 4; ++mt)
            #pragma unroll
            for (int r = 0; r < 4; ++r) {
                int m = mb * 128 + rowh + mt * 16 + quad * 4 + r;
                out[(size_t)m * C_ + n] = acc[mt][nt][r] + bias;
            }
    }
}

extern "C" void kernel_launch(void* const* d_in, const int* in_sizes, int n_in,
                              void* d_out, int out_size, void* d_ws, size_t ws_size,
                              hipStream_t stream) {
    const float* x  = (const float*)d_in[0];
    const float* Wq = (const float*)d_in[1];
    const float* Wk = (const float*)d_in[2];
    const float* Wv = (const float*)d_in[3];
    const float* Wo = (const float*)d_in[4];
    const float* bo = (const float*)d_in[5];
    float* out = (float*)d_out;
    char* ws = (char*)d_ws;
    u16* xbf  = (u16*)(ws + (size_t)0);           // 16 MB  x bf16 [8192,1024]
    u16* wt   = (u16*)(ws + ((size_t)16 << 20));  //  6 MB  W qkv [3072,1024] bf16
    u16* wobf = (u16*)(ws + ((size_t)22 << 20));  //  2 MB  Wo bf16 [1024,1024]
    u16* qb   = (u16*)(ws + ((size_t)24 << 20));  // 16 MB  q [BH,T,D]
    u16* kb   = (u16*)(ws + ((size_t)40 << 20));  // 16 MB  k [BH,T,D]
    u16* vb   = (u16*)(ws + ((size_t)56 << 20));  // 16 MB  v [BH,T,D]
    u16* vtb  = (u16*)(ws + ((size_t)72 << 20));  // 16 MB  v^T [BH,D,T]
    u16* attb = (u16*)(ws + ((size_t)88 << 20));  // 16 MB  att out [B*T,C]

    hipLaunchKernelGGL(cast_f32_bf16, dim3(BT * C_ / 1024), dim3(256), 0, stream, x, xbf);
    hipLaunchKernelGGL(cast_f32_bf16, dim3(C_ * C_ / 1024), dim3(256), 0, stream, Wo, wobf);
    hipLaunchKernelGGL(transpose_w, dim3(C_ / 64, H_, 3), dim3(256), 0, stream, Wq, Wk, Wv, wt);
    hipLaunchKernelGGL(qkv_gemm, dim3(BT / 128, 3 * C_ / 128), dim3(256), 0, stream, xbf, wt, qb, kb, vb);
    hipLaunchKernelGGL(vtrans, dim3(T_ / 64, BH), dim3(256), 0, stream, vb, vtb);
    hipLaunchKernelGGL(attn, dim3(BH, 16), dim3(256), 0, stream, qb, kb, vtb, attb);
    hipLaunchKernelGGL(out_gemm, dim3(BT / 128, C_ / 128), dim3(256), 0, stream, attb, wobf, bo, out);
}